// Round 7
// baseline (410.923 us; speedup 1.0000x reference)
//
#include <hip/hip_runtime.h>
#include <cmath>

#define BB 4
#define NN 4096
#define DD 244
#define DP 256
#define FSP 96
#define KC 3       // FSP/32 k-chunks for scores
#define NCH 4      // m-chunks per row
#define TCH 32     // m-tiles per chunk

typedef _Float16 half8 __attribute__((ext_vector_type(8)));
typedef float float4v __attribute__((ext_vector_type(4)));
typedef unsigned int uint;

#define MFMA16 __builtin_amdgcn_mfma_f32_16x16x32_f16

static __device__ __forceinline__ uint pack2(float a, float b) {
    _Float16 ha = (_Float16)a, hb = (_Float16)b;
    unsigned short ua = __builtin_bit_cast(unsigned short, ha);
    unsigned short ub = __builtin_bit_cast(unsigned short, hb);
    return (uint)ua | ((uint)ub << 16);
}

// ---------------- prep kernels ----------------
__global__ __launch_bounds__(256) void prep_w(const float* __restrict__ Wv,
                                              const float* __restrict__ Wo,
                                              _Float16* __restrict__ Wvh,
                                              _Float16* __restrict__ Woh) {
    int r = blockIdx.x, k = threadIdx.x;
    const float* src = blockIdx.y ? Wo : Wv;
    _Float16* dst = blockIdx.y ? Woh : Wvh;
    dst[(size_t)r * DP + k] =
        (r < DD && k < DD) ? (_Float16)src[(size_t)r * DD + k] : (_Float16)0.f;
}

// feature order: k 0..63 = shell, 64 = charge, 65 = sqrt(mass), 66..95 = 0
// Qb = -weight * feat  (so score = dot(Qb_n, Kb_m) - 0.3|n-m| = -energy)
__global__ __launch_bounds__(64) void prep_feat(const float* __restrict__ charge,
                                                const float* __restrict__ shell,
                                                const float* __restrict__ mass,
                                                _Float16* __restrict__ Qb,
                                                _Float16* __restrict__ Kb) {
    size_t row = blockIdx.x; int t = threadIdx.x;
    float v = shell[row * 64 + t];
    Kb[row * FSP + t] = (_Float16)v;
    Qb[row * FSP + t] = (_Float16)(-0.5f * v);
    int k2 = 64 + t;
    if (k2 < FSP) {
        float v2 = 0.f, q2 = 0.f;
        if (t == 0) { v2 = charge[row]; q2 = -1.0f * v2; }
        else if (t == 1) { v2 = sqrtf(mass[row]); q2 = -0.1f * v2; }
        Kb[row * FSP + k2] = (_Float16)v2;
        Qb[row * FSP + k2] = (_Float16)q2;
    }
}

// Vh [B*N][DP] f16 -> Vt [B][DP][N] f16
__global__ __launch_bounds__(256) void transpose_v(const _Float16* __restrict__ Vh,
                                                   _Float16* __restrict__ Vt) {
    __shared__ _Float16 tile[64][65];
    int n0 = blockIdx.x * 64, d0 = blockIdx.y * 64, b = blockIdx.z;
    int t = threadIdx.x;
#pragma unroll
    for (int i = 0; i < 16; ++i) {
        int idx = t + 256 * i;
        int r = idx >> 6, cc = idx & 63;
        tile[r][cc] = Vh[(size_t)(b * NN + n0 + r) * DP + d0 + cc];
    }
    __syncthreads();
#pragma unroll
    for (int i = 0; i < 16; ++i) {
        int idx = t + 256 * i;
        int dr = idx >> 6, nc = idx & 63;
        Vt[(size_t)b * DP * NN + (size_t)(d0 + dr) * NN + n0 + nc] = tile[nc][dr];
    }
}

// ---------------- 4-wave MFMA GEMM: C[r][c] = sum_k A[r][k]*W[c][k] + bias[c]
// block tile 64 rows x 128 cols; wave tile 32x64 (acc[2][4]); K = 256 (8 steps)
template <bool AF32, bool F16OUT>
__global__ __launch_bounds__(256) void gemm2(const void* __restrict__ A_,
                                             const _Float16* __restrict__ W,
                                             const float* __restrict__ bias,
                                             void* __restrict__ Cout) {
    int t = threadIdx.x;
    int w = t >> 6, l = t & 63, c = l & 15, g = l >> 4;
    int wr = w >> 1, wc = w & 1;
    int rowbase = blockIdx.x * 64 + wr * 32;
    int colbase = blockIdx.y * 128 + wc * 64;
    float4v acc[2][4];
#pragma unroll
    for (int i = 0; i < 2; ++i)
#pragma unroll
        for (int j = 0; j < 4; ++j) acc[i][j] = (float4v){0.f, 0.f, 0.f, 0.f};
#pragma unroll
    for (int kc = 0; kc < 8; ++kc) {
        int k0 = kc * 32 + g * 8;
        half8 af[2];
#pragma unroll
        for (int i = 0; i < 2; ++i) {
            int row = rowbase + 16 * i + c;
            if constexpr (AF32) {
                const float* ap = (const float*)A_ + (size_t)row * DD;
                float4 a0 = (k0 < DD) ? *(const float4*)(ap + k0) : make_float4(0, 0, 0, 0);
                float4 a1 = (k0 + 4 < DD) ? *(const float4*)(ap + k0 + 4) : make_float4(0, 0, 0, 0);
                af[i] = (half8){(_Float16)a0.x, (_Float16)a0.y, (_Float16)a0.z, (_Float16)a0.w,
                                (_Float16)a1.x, (_Float16)a1.y, (_Float16)a1.z, (_Float16)a1.w};
            } else {
                af[i] = *(const half8*)((const _Float16*)A_ + (size_t)row * DP + k0);
            }
        }
        half8 bf[4];
#pragma unroll
        for (int j = 0; j < 4; ++j)
            bf[j] = *(const half8*)(W + (size_t)(colbase + 16 * j + c) * DP + k0);
#pragma unroll
        for (int i = 0; i < 2; ++i)
#pragma unroll
            for (int j = 0; j < 4; ++j)
                acc[i][j] = MFMA16(af[i], bf[j], acc[i][j], 0, 0, 0);
    }
#pragma unroll
    for (int i = 0; i < 2; ++i)
#pragma unroll
        for (int j = 0; j < 4; ++j) {
            int col = colbase + 16 * j + c;
            float bcol = (col < DD) ? bias[col] : 0.f;
#pragma unroll
            for (int r = 0; r < 4; ++r) {
                int row = rowbase + 16 * i + 4 * g + r;
                float v = acc[i][j][r] + bcol;
                if constexpr (F16OUT) {
                    ((_Float16*)Cout)[(size_t)row * DP + col] = (_Float16)v;
                } else {
                    if (col < DD) ((float*)Cout)[(size_t)row * DD + col] = v;
                }
            }
        }
}

// ---------------- barrier-free wave-independent flash PV+stats ----------------
// Each WAVE owns 16 query rows (n0..n0+15) and one m-chunk (32 tiles = 1024 m),
// computing full-range stats (M,F,S) and the causal V-contraction over ALL of
// d=0..255. No cross-wave sharing -> no __syncthreads. P-fragment transpose via
// per-wave private LDS (same-wave lgkmcnt ordering only). Defer-max (THR=8)
// keeps rescales rare; e <= e^8 fits f16.
__global__ __launch_bounds__(256, 4) void pv_wave(const _Float16* __restrict__ Qb,
                                                  const _Float16* __restrict__ Kb,
                                                  const _Float16* __restrict__ Vt,
                                                  float* __restrict__ partS,
                                                  float* __restrict__ partO) {
    __shared__ __align__(16) uint Plds[4][16][20];  // per-wave P tile, stride 20 dw
    int t = threadIdx.x;
    int w = t >> 6, l = t & 63, c = l & 15, g = l >> 4;
    int gx = blockIdx.x * 4 + w;     // wave unit within batch: 0..1023
    int b = blockIdx.y;
    int nb = gx & 255;               // 16-row block index
    int ch = gx >> 8;                // m-chunk 0..3
    int n0 = nb * 16;
    size_t bN = (size_t)b * NN;

    half8 qf[KC];
#pragma unroll
    for (int kc = 0; kc < KC; ++kc)
        qf[kc] = *(const half8*)(Qb + (bN + n0 + c) * FSP + kc * 32 + g * 8);

    float Mu = -1e30f, F = 0.f, S = 0.f;
    float4v acc[16];
#pragma unroll
    for (int dc = 0; dc < 16; ++dc) acc[dc] = (float4v){0.f, 0.f, 0.f, 0.f};
    const _Float16* VtB = Vt + (size_t)b * DP * NN + (size_t)c * NN + g * 8;
    float nf = (float)(n0 + c);
    int nqi = n0 + c;

    for (int tt = 0; tt < TCH; ++tt) {
        int m0 = (ch * TCH + tt) * 32;
        // ---- scores: 2 x (3-MFMA chain) ----
        half8 kf0[KC], kf1[KC];
        const _Float16* kb0 = Kb + (bN + m0 + c) * FSP + g * 8;
#pragma unroll
        for (int kc = 0; kc < KC; ++kc) {
            kf0[kc] = *(const half8*)(kb0 + kc * 32);
            kf1[kc] = *(const half8*)(kb0 + 16 * FSP + kc * 32);
        }
        float4v p0 = (float4v){0.f, 0.f, 0.f, 0.f};
        float4v p1 = (float4v){0.f, 0.f, 0.f, 0.f};
#pragma unroll
        for (int kc = 0; kc < KC; ++kc) p0 = MFMA16(kf0[kc], qf[kc], p0, 0, 0, 0);
#pragma unroll
        for (int kc = 0; kc < KC; ++kc) p1 = MFMA16(kf1[kc], qf[kc], p1, 0, 0, 0);
        float sv[8];
        float df = nf - (float)(m0 + 4 * g);
#pragma unroll
        for (int r = 0; r < 4; ++r) {
            sv[r]     = p0[r] - 0.3f * fabsf(df - (float)r);
            sv[4 + r] = p1[r] - 0.3f * fabsf(df - (float)(16 + r));
        }
        // ---- row max (rows = n0+c; reduce over g groups) ----
        float tm = sv[0];
#pragma unroll
        for (int i = 1; i < 8; ++i) tm = fmaxf(tm, sv[i]);
        tm = fmaxf(tm, __shfl_xor(tm, 16));
        tm = fmaxf(tm, __shfl_xor(tm, 32));
        // ---- deferred rescale (trigger only if max grew past THR=8) ----
        if (!__all(tm <= Mu + 8.f)) {
            float Mn = fmaxf(Mu, tm);
            float corr = __expf(Mu - Mn);
            F *= corr; S *= corr; Mu = Mn;
            float cr[4];
#pragma unroll
            for (int r = 0; r < 4; ++r) cr[r] = __shfl(corr, 4 * g + r);
#pragma unroll
            for (int dc = 0; dc < 16; ++dc)
#pragma unroll
                for (int r = 0; r < 4; ++r) acc[dc][r] *= cr[r];
        }
        // ---- exp, stats, masked P ----
        uint pk[4];
#pragma unroll
        for (int s2 = 0; s2 < 2; ++s2) {
            float wr[4];
#pragma unroll
            for (int r = 0; r < 4; ++r) {
                int m = m0 + 16 * s2 + 4 * g + r;
                float e = __expf(sv[4 * s2 + r] - Mu);
                F += e;
                float wm = (m <= nqi) ? e : 0.f;
                S += wm;
                wr[r] = wm;
            }
            pk[2 * s2]     = pack2(wr[0], wr[1]);
            pk[2 * s2 + 1] = pack2(wr[2], wr[3]);
        }
        // ---- causal PV via per-wave LDS transpose ----
        if (m0 <= n0 + 15) {
            uint* dst = &Plds[w][c][2 * g];
            dst[0] = pk[0]; dst[1] = pk[1];
            dst[8] = pk[2]; dst[9] = pk[3];
            half8 pa = *(const half8*)&Plds[w][c][4 * g];
#pragma unroll
            for (int dc = 0; dc < 16; ++dc) {
                half8 vf = *(const half8*)(VtB + (size_t)(dc * 16) * NN + m0);
                acc[dc] = MFMA16(pa, vf, acc[dc], 0, 0, 0);
            }
        }
    }
    // ---- reduce F,S over g; write per-chunk stats ----
    F += __shfl_xor(F, 16); F += __shfl_xor(F, 32);
    S += __shfl_xor(S, 16); S += __shfl_xor(S, 32);
    if (l < 16) {
        size_t bn = bN + n0 + c;
        size_t idx = ((size_t)ch * (BB * NN) + bn) * 3;
        partS[idx + 0] = Mu;
        partS[idx + 1] = F;
        partS[idx + 2] = S;
    }
    // ---- write unscaled acc partial if chunk overlaps causal range ----
    if (ch <= (nb >> 6)) {
#pragma unroll
        for (int r = 0; r < 4; ++r) {
            int nn = n0 + 4 * g + r;
            size_t base = ((size_t)ch * (BB * NN) + bN + nn) * DP;
#pragma unroll
            for (int dc = 0; dc < 16; ++dc)
                partO[base + dc * 16 + c] = acc[dc][r];
        }
    }
}

// ---------------- finalize: merge chunk partials -> alpha -> Oh ----------------
__global__ __launch_bounds__(256) void finalize(const float* __restrict__ partS,
                                                const float* __restrict__ partO,
                                                const float* __restrict__ valence,
                                                _Float16* __restrict__ Oh) {
    int n = blockIdx.x, b = blockIdx.y;
    size_t bn = (size_t)b * NN + n;
    int d = threadIdx.x;
    float Ms[NCH], Fs[NCH], Ss[NCH];
    float M = -1e30f;
#pragma unroll
    for (int ch = 0; ch < NCH; ++ch) {
        size_t idx = ((size_t)ch * (BB * NN) + bn) * 3;
        Ms[ch] = partS[idx + 0]; Fs[ch] = partS[idx + 1]; Ss[ch] = partS[idx + 2];
        M = fmaxf(M, Ms[ch]);
    }
    float F = 0.f, S = 0.f;
#pragma unroll
    for (int ch = 0; ch < NCH; ++ch) {
        float wc = __expf(Ms[ch] - M);
        F += Fs[ch] * wc; S += Ss[ch] * wc;
    }
    float val = valence[bn];
    float scale = fminf(val / (1.0f + 1e-6f), 1.0f);
    float alpha = scale / (scale * S + 1e-8f * F);
    int nch = (n >> 10) + 1;  // chunks containing causal m for this row
    float o = 0.f;
    for (int ch = 0; ch < nch; ++ch)
        o += __expf(Ms[ch] - M) * partO[((size_t)ch * (BB * NN) + bn) * DP + d];
    Oh[bn * DP + d] = (_Float16)(alpha * o);
}

// ---------------- launch ----------------
extern "C" void kernel_launch(void* const* d_in, const int* in_sizes, int n_in,
                              void* d_out, int out_size, void* d_ws, size_t ws_size,
                              hipStream_t stream) {
    (void)in_sizes; (void)n_in; (void)out_size; (void)ws_size;
    const float* charge  = (const float*)d_in[0];
    const float* shell   = (const float*)d_in[1];
    const float* mass    = (const float*)d_in[2];
    const float* valence = (const float*)d_in[3];
    const float* x  = (const float*)d_in[5];
    const float* Wv = (const float*)d_in[6];
    const float* bv = (const float*)d_in[7];
    const float* Wo = (const float*)d_in[8];
    const float* bo = (const float*)d_in[9];
    float* out = (float*)d_out;

    const size_t BN = (size_t)BB * NN;
    char* w = (char*)d_ws;
    _Float16* Qb  = (_Float16*)w;              w += BN * FSP * 2;             // 3.1 MB
    _Float16* Kb  = (_Float16*)w;              w += BN * FSP * 2;             // 3.1 MB
    _Float16* Vh  = (_Float16*)w;              w += BN * DP * 2;              // 8.4 MB (reused as Oh)
    _Float16* Vt  = (_Float16*)w;              w += BN * DP * 2;              // 8.4 MB
    _Float16* Wvh = (_Float16*)w;              w += DP * DP * 2;
    _Float16* Woh = (_Float16*)w;              w += DP * DP * 2;
    float* partS  = (float*)w;                 w += (size_t)NCH * BN * 3 * 4;  // 0.8 MB
    float* partO  = (float*)w;                 w += (size_t)NCH * BN * DP * 4; // 67 MB
    _Float16* Oh = Vh;  // Vh dead after transpose_v

    prep_w<<<dim3(DP, 2), 256, 0, stream>>>(Wv, Wo, Wvh, Woh);
    prep_feat<<<BB * NN, 64, 0, stream>>>(charge, shell, mass, Qb, Kb);
    gemm2<true, true><<<dim3(BB * NN / 64, DP / 128), 256, 0, stream>>>(x, Wvh, bv, (void*)Vh);
    transpose_v<<<dim3(NN / 64, DP / 64, BB), 256, 0, stream>>>(Vh, Vt);
    pv_wave<<<dim3(256, BB), 256, 0, stream>>>(Qb, Kb, Vt, partS, partO);
    finalize<<<dim3(NN, BB), 256, 0, stream>>>(partS, partO, valence, Oh);
    gemm2<false, false><<<dim3(BB * NN / 64, DP / 128), 256, 0, stream>>>(Oh, Woh, bo, (void*)out);
}

// Round 8
// 286.513 us; speedup vs baseline: 1.4342x; 1.4342x over previous
//
#include <hip/hip_runtime.h>
#include <cmath>

#define BB 4
#define NN 4096
#define DD 244
#define DP 256
#define FSP 96
#define KC 3       // FSP/32 k-chunks for scores
#define MSPLIT 8   // m-chunks for stats
#define TPC ((NN / 32) / MSPLIT)  // tiles per stats chunk = 16
#define NCH 4      // m-chunks (1024 rows) for pv partials
#define WV 4       // waves per pv block

typedef _Float16 half8 __attribute__((ext_vector_type(8)));
typedef float float4v __attribute__((ext_vector_type(4)));
typedef unsigned int uint;

#define MFMA16 __builtin_amdgcn_mfma_f32_16x16x32_f16

static __device__ __forceinline__ uint pack2(float a, float b) {
    _Float16 ha = (_Float16)a, hb = (_Float16)b;
    unsigned short ua = __builtin_bit_cast(unsigned short, ha);
    unsigned short ub = __builtin_bit_cast(unsigned short, hb);
    return (uint)ua | ((uint)ub << 16);
}

// ---------------- prep: Wqt[c][k] = sum_j Wo[c][j] Wv[j][k]; uo = Wo @ bv ----------------
__global__ __launch_bounds__(256) void prep_wq(const float* __restrict__ Wv,
                                               const float* __restrict__ Wo,
                                               const float* __restrict__ bv,
                                               _Float16* __restrict__ Wqt,
                                               float* __restrict__ uo) {
    int k = blockIdx.x * 16 + (threadIdx.x & 15);
    int c = blockIdx.y * 16 + (threadIdx.x >> 4);
    float acc = 0.f;
    if (c < DD && k < DD)
        for (int j = 0; j < DD; ++j) acc += Wo[(size_t)c * DD + j] * Wv[(size_t)j * DD + k];
    Wqt[(size_t)c * DP + k] = (_Float16)acc;
    if (blockIdx.x == 0 && (threadIdx.x & 15) == 0) {
        float u = 0.f;
        if (c < DD)
            for (int kk = 0; kk < DD; ++kk) u += bv[kk] * Wo[(size_t)c * DD + kk];
        uo[c] = u;
    }
}

// feature order: k 0..63 = shell, 64 = charge, 65 = sqrt(mass), 66..95 = 0
// Qb = -weight * feat  (so score = dot(Qb_n, Kb_m) - 0.3|n-m| = -energy)
__global__ __launch_bounds__(64) void prep_feat(const float* __restrict__ charge,
                                                const float* __restrict__ shell,
                                                const float* __restrict__ mass,
                                                _Float16* __restrict__ Qb,
                                                _Float16* __restrict__ Kb) {
    size_t row = blockIdx.x; int t = threadIdx.x;
    float v = shell[row * 64 + t];
    Kb[row * FSP + t] = (_Float16)v;
    Qb[row * FSP + t] = (_Float16)(-0.5f * v);
    int k2 = 64 + t;
    if (k2 < FSP) {
        float v2 = 0.f, q2 = 0.f;
        if (t == 0) { v2 = charge[row]; q2 = -1.0f * v2; }
        else if (t == 1) { v2 = sqrtf(mass[row]); q2 = -0.1f * v2; }
        Kb[row * FSP + k2] = (_Float16)v2;
        Qb[row * FSP + k2] = (_Float16)q2;
    }
}

// Uh [B*N][DP] f16 -> Ut [B][DP][N] f16
__global__ __launch_bounds__(256) void transpose_v(const _Float16* __restrict__ Vh,
                                                   _Float16* __restrict__ Vt) {
    __shared__ _Float16 tile[64][65];
    int n0 = blockIdx.x * 64, d0 = blockIdx.y * 64, b = blockIdx.z;
    int t = threadIdx.x;
#pragma unroll
    for (int i = 0; i < 16; ++i) {
        int idx = t + 256 * i;
        int r = idx >> 6, cc = idx & 63;
        tile[r][cc] = Vh[(size_t)(b * NN + n0 + r) * DP + d0 + cc];
    }
    __syncthreads();
#pragma unroll
    for (int i = 0; i < 16; ++i) {
        int idx = t + 256 * i;
        int dr = idx >> 6, nc = idx & 63;
        Vt[(size_t)b * DP * NN + (size_t)(d0 + dr) * NN + n0 + nc] = tile[nc][dr];
    }
}

// ---------------- 4-wave MFMA GEMM: C[r][c] = sum_k A[r][k]*W[c][k] + bias[c] ----------------
template <bool AF32, bool F16OUT>
__global__ __launch_bounds__(256) void gemm2(const void* __restrict__ A_,
                                             const _Float16* __restrict__ W,
                                             const float* __restrict__ bias,
                                             void* __restrict__ Cout) {
    int t = threadIdx.x;
    int w = t >> 6, l = t & 63, c = l & 15, g = l >> 4;
    int wr = w >> 1, wc = w & 1;
    int rowbase = blockIdx.x * 64 + wr * 32;
    int colbase = blockIdx.y * 128 + wc * 64;
    float4v acc[2][4];
#pragma unroll
    for (int i = 0; i < 2; ++i)
#pragma unroll
        for (int j = 0; j < 4; ++j) acc[i][j] = (float4v){0.f, 0.f, 0.f, 0.f};
#pragma unroll
    for (int kc = 0; kc < 8; ++kc) {
        int k0 = kc * 32 + g * 8;
        half8 af[2];
#pragma unroll
        for (int i = 0; i < 2; ++i) {
            int row = rowbase + 16 * i + c;
            if constexpr (AF32) {
                const float* ap = (const float*)A_ + (size_t)row * DD;
                float4 a0 = (k0 < DD) ? *(const float4*)(ap + k0) : make_float4(0, 0, 0, 0);
                float4 a1 = (k0 + 4 < DD) ? *(const float4*)(ap + k0 + 4) : make_float4(0, 0, 0, 0);
                af[i] = (half8){(_Float16)a0.x, (_Float16)a0.y, (_Float16)a0.z, (_Float16)a0.w,
                                (_Float16)a1.x, (_Float16)a1.y, (_Float16)a1.z, (_Float16)a1.w};
            } else {
                af[i] = *(const half8*)((const _Float16*)A_ + (size_t)row * DP + k0);
            }
        }
        half8 bf[4];
#pragma unroll
        for (int j = 0; j < 4; ++j)
            bf[j] = *(const half8*)(W + (size_t)(colbase + 16 * j + c) * DP + k0);
#pragma unroll
        for (int i = 0; i < 2; ++i)
#pragma unroll
            for (int j = 0; j < 4; ++j)
                acc[i][j] = MFMA16(af[i], bf[j], acc[i][j], 0, 0, 0);
    }
#pragma unroll
    for (int i = 0; i < 2; ++i)
#pragma unroll
        for (int j = 0; j < 4; ++j) {
            int col = colbase + 16 * j + c;
            float bcol = (col < DD) ? bias[col] : 0.f;
#pragma unroll
            for (int r = 0; r < 4; ++r) {
                int row = rowbase + 16 * i + 4 * g + r;
                float v = acc[i][j][r] + bcol;
                if constexpr (F16OUT) {
                    ((_Float16*)Cout)[(size_t)row * DP + col] = (_Float16)v;
                } else {
                    if (col < DD) ((float*)Cout)[(size_t)row * DD + col] = v;
                }
            }
        }
}

// ---------------- stats stage A: per (row, m-chunk) partial (M, F, S) ----------------
// barrier-free, no LDS: one 64-thread wave per (32-row block, chunk, batch)
__global__ __launch_bounds__(64) void stats_partial(const _Float16* __restrict__ Qb,
                                                    const _Float16* __restrict__ Kb,
                                                    float* __restrict__ partS) {
    int l = threadIdx.x, c = l & 15, g = l >> 4;
    int bx = blockIdx.x, chunk = blockIdx.y, b = blockIdx.z;
    size_t bN = (size_t)b * NN;
    int n0 = bx * 32;
    half8 qf[2][KC];
#pragma unroll
    for (int qg = 0; qg < 2; ++qg)
#pragma unroll
        for (int kc = 0; kc < KC; ++kc)
            qf[qg][kc] = *(const half8*)(Qb + (bN + n0 + 16 * qg + c) * FSP + kc * 32 + g * 8);
    int n[2] = {n0 + c, n0 + 16 + c};
    float M[2] = {-1e30f, -1e30f}, F[2] = {0.f, 0.f}, S[2] = {0.f, 0.f};
    int m_lo = chunk * TPC * 32, m_hi = m_lo + TPC * 32;
    for (int m0 = m_lo; m0 < m_hi; m0 += 32) {
        half8 kf[2][KC];
#pragma unroll
        for (int s = 0; s < 2; ++s)
#pragma unroll
            for (int kc = 0; kc < KC; ++kc)
                kf[s][kc] = *(const half8*)(Kb + (bN + m0 + 16 * s + c) * FSP + kc * 32 + g * 8);
#pragma unroll
        for (int qg = 0; qg < 2; ++qg) {
            float sv[8];
#pragma unroll
            for (int s = 0; s < 2; ++s) {
                float4v p = (float4v){0.f, 0.f, 0.f, 0.f};
#pragma unroll
                for (int kc = 0; kc < KC; ++kc) p = MFMA16(kf[s][kc], qf[qg][kc], p, 0, 0, 0);
#pragma unroll
                for (int r = 0; r < 4; ++r) {
                    int m = m0 + 16 * s + 4 * g + r;
                    sv[4 * s + r] = p[r] - 0.3f * fabsf((float)(n[qg] - m));
                }
            }
            float t = sv[0];
#pragma unroll
            for (int i = 1; i < 8; ++i) t = fmaxf(t, sv[i]);
            float Mn = fmaxf(M[qg], t);
            float corr = __expf(M[qg] - Mn);
            F[qg] *= corr; S[qg] *= corr; M[qg] = Mn;
#pragma unroll
            for (int s = 0; s < 2; ++s)
#pragma unroll
                for (int r = 0; r < 4; ++r) {
                    int m = m0 + 16 * s + 4 * g + r;
                    float e = __expf(sv[4 * s + r] - M[qg]);
                    F[qg] += e;
                    S[qg] += (m <= n[qg]) ? e : 0.f;
                }
        }
    }
#pragma unroll
    for (int qg = 0; qg < 2; ++qg) {
#pragma unroll
        for (int off = 16; off <= 32; off <<= 1) {
            float Mo = __shfl_xor(M[qg], off);
            float Fo = __shfl_xor(F[qg], off);
            float So = __shfl_xor(S[qg], off);
            float Mn = fmaxf(M[qg], Mo);
            float ca = __expf(M[qg] - Mn), cb2 = __expf(Mo - Mn);
            F[qg] = F[qg] * ca + Fo * cb2;
            S[qg] = S[qg] * ca + So * cb2;
            M[qg] = Mn;
        }
    }
    if (l < 32) {
        int qg = g;
        size_t bn = bN + n0 + 16 * qg + c;
        size_t idx = ((size_t)chunk * (BB * NN) + bn) * 3;
        partS[idx + 0] = M[qg];
        partS[idx + 1] = F[qg];
        partS[idx + 2] = S[qg];
    }
}

// ---------------- stats stage B: merge chunks, compute alpha ----------------
__global__ __launch_bounds__(256) void stats_merge(const float* __restrict__ partS,
                                                   const float* __restrict__ valence,
                                                   float* __restrict__ rowstats) {
    size_t bn = (size_t)blockIdx.x * 256 + threadIdx.x;
    float M = -1e30f, F = 0.f, S = 0.f;
#pragma unroll
    for (int ch = 0; ch < MSPLIT; ++ch) {
        size_t idx = ((size_t)ch * (BB * NN) + bn) * 3;
        float m = partS[idx + 0], f = partS[idx + 1], s = partS[idx + 2];
        float Mn = fmaxf(M, m);
        float ca = __expf(M - Mn), cb2 = __expf(m - Mn);
        F = F * ca + f * cb2;
        S = S * ca + s * cb2;
        M = Mn;
    }
    float val = valence[bn];
    float scale = fminf(val / (1.0f + 1e-6f), 1.0f);
    float alpha = scale / (scale * S + 1e-8f * F);
    rowstats[bn * 2 + 0] = M;
    rowstats[bn * 2 + 1] = alpha;
}

// ---------------- PV (round-5 proven structure): 4 waves produce P tiles,
// consume own dc-quarter. bx<32 single-chunk blocks write f32 out (+bo);
// others write fp32 partials per chunk.
__global__ __launch_bounds__(256) void pv16(const _Float16* __restrict__ Qb,
                                            const _Float16* __restrict__ Kb,
                                            const _Float16* __restrict__ Ut,
                                            const float* __restrict__ rowstats,
                                            const float* __restrict__ bo,
                                            float* __restrict__ out,
                                            float* __restrict__ partO) {
    __shared__ __align__(16) uint Plds[2][WV][2][16][20];
    int t = threadIdx.x;
    int w = t >> 6, l = t & 63, c = l & 15, g = l >> 4;
    int gx = blockIdx.x, b = blockIdx.y;
    int bx, ch;
    if (gx < 32)       { bx = gx; ch = 0; }
    else if (gx < 96)  { int r = gx - 32;  bx = 32 + (r >> 1); ch = r & 1; }
    else if (gx < 192) { int r = gx - 96;  bx = 64 + r / 3;    ch = r % 3; }
    else               { int r = gx - 192; bx = 96 + (r >> 2); ch = r & 3; }
    int t0 = ch * 32;
    int t1 = min(t0 + 32, bx + 1);
    bool direct = (bx < 32);

    size_t bN = (size_t)b * NN;
    int n0 = bx * 32;
    half8 qf[2][KC];
#pragma unroll
    for (int qg = 0; qg < 2; ++qg)
#pragma unroll
        for (int kc = 0; kc < KC; ++kc)
            qf[qg][kc] = *(const half8*)(Qb + (bN + n0 + 16 * qg + c) * FSP + kc * 32 + g * 8);
    int nq[2] = {n0 + c, n0 + 16 + c};
    float Mq[2], Aq[2];
#pragma unroll
    for (int qg = 0; qg < 2; ++qg) {
        Mq[qg] = rowstats[(bN + n0 + 16 * qg + c) * 2 + 0];
        Aq[qg] = rowstats[(bN + n0 + 16 * qg + c) * 2 + 1];
    }
    float4v acc[2][4];
#pragma unroll
    for (int qg = 0; qg < 2; ++qg)
#pragma unroll
        for (int d = 0; d < 4; ++d) acc[qg][d] = (float4v){0.f, 0.f, 0.f, 0.f};
    const _Float16* UtB = Ut + (size_t)b * DP * NN;

    int nt = t1 - t0;
    int rounds = (nt + WV - 1) / WV;
    for (int ro = 0; ro < rounds; ++ro) {
        int bufi = ro & 1;
        int tt = t0 + ro * WV + w;
        if (tt < t1) {
            int m0 = tt * 32;
            half8 kf[2][KC];
#pragma unroll
            for (int s = 0; s < 2; ++s)
#pragma unroll
                for (int kc = 0; kc < KC; ++kc)
                    kf[s][kc] = *(const half8*)(Kb + (bN + m0 + 16 * s + c) * FSP + kc * 32 + g * 8);
#pragma unroll
            for (int qg = 0; qg < 2; ++qg) {
#pragma unroll
                for (int s = 0; s < 2; ++s) {
                    float4v p = (float4v){0.f, 0.f, 0.f, 0.f};
#pragma unroll
                    for (int kc = 0; kc < KC; ++kc) p = MFMA16(kf[s][kc], qf[qg][kc], p, 0, 0, 0);
                    float wv[4];
#pragma unroll
                    for (int r = 0; r < 4; ++r) {
                        int m = m0 + 16 * s + 4 * g + r;
                        float sc = p[r] - 0.3f * fabsf((float)(nq[qg] - m));
                        wv[r] = (m <= nq[qg]) ? __expf(sc - Mq[qg]) : 0.f;
                    }
                    uint* dst = &Plds[bufi][w][qg][c][8 * s + 2 * g];
                    dst[0] = pack2(wv[0], wv[1]);
                    dst[1] = pack2(wv[2], wv[3]);
                }
            }
        }
        __syncthreads();
        int lim = (nt - ro * WV < WV) ? (nt - ro * WV) : WV;
        for (int ww = 0; ww < lim; ++ww) {
            int m0p = (t0 + ro * WV + ww) * 32;
            half8 pa0 = *(const half8*)&Plds[bufi][ww][0][c][4 * g];
            half8 pa1 = *(const half8*)&Plds[bufi][ww][1][c][4 * g];
#pragma unroll
            for (int dcl = 0; dcl < 4; ++dcl) {
                int dc = 4 * w + dcl;
                half8 vf = *(const half8*)(UtB + (size_t)(dc * 16 + c) * NN + m0p + g * 8);
                acc[0][dcl] = MFMA16(pa0, vf, acc[0][dcl], 0, 0, 0);
                acc[1][dcl] = MFMA16(pa1, vf, acc[1][dcl], 0, 0, 0);
            }
        }
    }
    if (direct) {
#pragma unroll
        for (int qg = 0; qg < 2; ++qg)
#pragma unroll
            for (int r = 0; r < 4; ++r) {
                float a = __shfl(Aq[qg], 4 * g + r);
                int nn = n0 + 16 * qg + 4 * g + r;
#pragma unroll
                for (int dcl = 0; dcl < 4; ++dcl) {
                    int col = (4 * w + dcl) * 16 + c;
                    if (col < DD)
                        out[(bN + nn) * DD + col] = a * acc[qg][dcl][r] + bo[col];
                }
            }
    } else {
#pragma unroll
        for (int qg = 0; qg < 2; ++qg)
#pragma unroll
            for (int r = 0; r < 4; ++r) {
                int nn = n0 + 16 * qg + 4 * g + r;
                size_t base = ((size_t)ch * (BB * NN) + bN + nn) * DP;
#pragma unroll
                for (int dcl = 0; dcl < 4; ++dcl)
                    partO[base + (4 * w + dcl) * 16 + c] = acc[qg][dcl][r];
            }
    }
}

// rows n >= 1024: out = alpha * sum_ch partO[ch] + bo
__global__ __launch_bounds__(256) void pv_merge(const float* __restrict__ partO,
                                                const float* __restrict__ rowstats,
                                                const float* __restrict__ bo,
                                                float* __restrict__ out) {
    int n = 1024 + blockIdx.x;
    int b = blockIdx.y;
    size_t bn = (size_t)b * NN + n;
    int d = threadIdx.x;
    if (d >= DD) return;
    int nc = (n >> 10) + 1;
    float s = 0.f;
    for (int cc = 0; cc < nc; ++cc)
        s += partO[((size_t)cc * (BB * NN) + bn) * DP + d];
    float alpha = rowstats[bn * 2 + 1];
    out[bn * DD + d] = alpha * s + bo[d];
}

// ---------------- launch ----------------
extern "C" void kernel_launch(void* const* d_in, const int* in_sizes, int n_in,
                              void* d_out, int out_size, void* d_ws, size_t ws_size,
                              hipStream_t stream) {
    (void)in_sizes; (void)n_in; (void)out_size; (void)ws_size;
    const float* charge  = (const float*)d_in[0];
    const float* shell   = (const float*)d_in[1];
    const float* mass    = (const float*)d_in[2];
    const float* valence = (const float*)d_in[3];
    const float* x  = (const float*)d_in[5];
    const float* Wv = (const float*)d_in[6];
    const float* bv = (const float*)d_in[7];
    const float* Wo = (const float*)d_in[8];
    const float* bo = (const float*)d_in[9];
    float* out = (float*)d_out;

    const size_t BN = (size_t)BB * NN;
    char* w = (char*)d_ws;
    _Float16* Qb  = (_Float16*)w;              w += BN * FSP * 2;              // 3.1 MB
    _Float16* Kb  = (_Float16*)w;              w += BN * FSP * 2;              // 3.1 MB
    _Float16* Uh  = (_Float16*)w;              w += BN * DP * 2;               // 8.4 MB
    _Float16* Ut  = (_Float16*)w;              w += BN * DP * 2;               // 8.4 MB
    _Float16* Wqt = (_Float16*)w;              w += DP * DP * 2;               // 128 KB
    float* uo     = (float*)w;                 w += DP * 4;
    float* rowstats = (float*)w;               w += BN * 2 * 4;                // 128 KB
    float* partS  = (float*)w;                 w += (size_t)MSPLIT * BN * 3 * 4; // 1.6 MB
    float* partO  = (float*)w;                 w += (size_t)NCH * BN * DP * 4;   // 67 MB

    prep_wq<<<dim3(DP / 16, DP / 16), 256, 0, stream>>>(Wv, Wo, bv, Wqt, uo);
    prep_feat<<<BB * NN, 64, 0, stream>>>(charge, shell, mass, Qb, Kb);
    gemm2<true, true><<<dim3(BB * NN / 64, DP / 128), 256, 0, stream>>>(x, Wqt, uo, (void*)Uh);
    transpose_v<<<dim3(NN / 64, DP / 64, BB), 256, 0, stream>>>(Uh, Ut);
    stats_partial<<<dim3(NN / 32, MSPLIT, BB), 64, 0, stream>>>(Qb, Kb, partS);
    stats_merge<<<BN / 256, 256, 0, stream>>>(partS, valence, rowstats);
    pv16<<<dim3(320, BB), 256, 0, stream>>>(Qb, Kb, Ut, rowstats, bo, out, partO);
    pv_merge<<<dim3(NN - 1024, BB), 256, 0, stream>>>(partO, rowstats, bo, out);
}